// Round 4
// baseline (257.662 us; speedup 1.0000x reference)
//
#include <hip/hip_runtime.h>
#include <math.h>

using bf16x8 = __attribute__((ext_vector_type(8))) short;
using f32x4  = __attribute__((ext_vector_type(4))) float;

struct __align__(8) us4 { unsigned short x, y, z, w; };
struct __align__(8) u32x2 { unsigned int x, y; };

__device__ __forceinline__ unsigned short f2b(float f) {
  union { float f; unsigned u; } v; v.f = f;
  unsigned r = v.u + 0x7FFFu + ((v.u >> 16) & 1u);
  return (unsigned short)(r >> 16);
}
__device__ __forceinline__ float b2f(unsigned short b) {
  union { unsigned u; float f; } v; v.u = ((unsigned)b) << 16;
  return v.f;
}
__device__ __forceinline__ unsigned int cvt_pk_bf16(float lo, float hi) {
  unsigned int d;
  asm("v_cvt_pk_bf16_f32 %0, %1, %2" : "=v"(d) : "v"(lo), "v"(hi));
  return d;
}

#define GLDS(g, l) __builtin_amdgcn_global_load_lds(                        \
    (const __attribute__((address_space(1))) void*)(g),                    \
    (__attribute__((address_space(3))) void*)(l), 16, 0, 0)

// ---------------------------------------------------------------------------
// Weight transpose + fp32->bf16 convert:  src[K][N] (f32) -> dst[N][K] (bf16)
// ---------------------------------------------------------------------------
__global__ void __launch_bounds__(256) transpose_w(
    const float* __restrict__ src, unsigned short* __restrict__ dst,
    int K, int N) {
  __shared__ float tile[32][33];
  const int n0 = blockIdx.x * 32, k0 = blockIdx.y * 32;
  const int tx = threadIdx.x & 31, ty = threadIdx.x >> 5;  // 32 x 8
#pragma unroll
  for (int i = 0; i < 32; i += 8)
    tile[ty + i][tx] = src[(size_t)(k0 + ty + i) * N + n0 + tx];
  __syncthreads();
#pragma unroll
  for (int i = 0; i < 32; i += 8)
    dst[(size_t)(n0 + ty + i) * K + k0 + tx] = f2b(tile[tx][ty + i]);
}

// ---------------------------------------------------------------------------
// LayerNorm over last dim (1024), fp32 in -> bf16 out
// ---------------------------------------------------------------------------
__global__ void __launch_bounds__(256) ln_kernel(
    const float* __restrict__ in, const float* __restrict__ scale,
    const float* __restrict__ shift, unsigned short* __restrict__ out) {
  const int row = blockIdx.x, t = threadIdx.x;
  const float4 v = ((const float4*)(in + (size_t)row * 1024))[t];
  float s  = v.x + v.y + v.z + v.w;
  float s2 = v.x * v.x + v.y * v.y + v.z * v.z + v.w * v.w;
#pragma unroll
  for (int off = 32; off; off >>= 1) {
    s  += __shfl_xor(s,  off);
    s2 += __shfl_xor(s2, off);
  }
  __shared__ float red[8];
  const int w = t >> 6, lane = t & 63;
  if (!lane) { red[w] = s; red[4 + w] = s2; }
  __syncthreads();
  s  = red[0] + red[1] + red[2] + red[3];
  s2 = red[4] + red[5] + red[6] + red[7];
  const float mean = s * (1.0f / 1024.0f);
  const float var  = s2 * (1.0f / 1024.0f) - mean * mean;
  const float rstd = rsqrtf(var + 1e-5f);
  const float4 sc = ((const float4*)scale)[t];
  const float4 sh = ((const float4*)shift)[t];
  us4 o;
  o.x = f2b((v.x - mean) * rstd * sc.x + sh.x);
  o.y = f2b((v.y - mean) * rstd * sc.y + sh.y);
  o.z = f2b((v.z - mean) * rstd * sc.z + sh.z);
  o.w = f2b((v.w - mean) * rstd * sc.w + sh.w);
  ((us4*)(out + (size_t)row * 1024))[t] = o;
}

// ---------------------------------------------------------------------------
// GEMM: C[M,N] = A[M,K](bf16) * B^T with B stored as [N,K](bf16).
// BMx128 tile, BK=64, 4 waves. Double-buffered LDS, single barrier per
// K-step (T3-min). Pointers/offsets hoisted out of the K-loop.
// MODE 0: qkv split -> qk bf16 [4096][2048] + vt bf16 [2][1024][2048] (V^T)
// MODE 1: out_f32 = acc + resid
// MODE 2: out_bf16 = gelu_tanh(acc + bias)
// MODE 3: out_f32 = acc + bias + resid
// ---------------------------------------------------------------------------
template <int MODE, int BM>
__global__ void __launch_bounds__(256) gemm_bt(
    const unsigned short* __restrict__ A, const unsigned short* __restrict__ B,
    int K, int N,
    float* __restrict__ outf, unsigned short* __restrict__ outb,
    const float* __restrict__ bias, const float* __restrict__ resid,
    unsigned short* __restrict__ vt) {
  constexpr int WN = (BM == 128) ? 2 : 4;   // waves along N
  constexpr int NJ = 128 / (16 * WN);       // N-fragments per wave
  constexpr int ACH = BM / 32;              // A staging passes
  __shared__ unsigned short lA[2][BM * 64];
  __shared__ unsigned short lB[2][128 * 64];
  const int t = threadIdx.x, lane = t & 63;
  const int w = t >> 6, wm = w / WN, wn = w % WN;
  const int r16 = lane & 15, g = lane >> 4;
  const int m0 = blockIdx.x * BM, n0 = blockIdx.y * 128;

  const unsigned short* aSrc[ACH];
  const unsigned short* bSrc[4];
#pragma unroll
  for (int p = 0; p < ACH; ++p) {
    const int ci = t + p * 256, m = ci >> 3, cs = ci & 7;
    aSrc[p] = A + (size_t)(m0 + m) * K + (cs ^ (m & 7)) * 8;
  }
#pragma unroll
  for (int p = 0; p < 4; ++p) {
    const int ci = t + p * 256, m = ci >> 3, cs = ci & 7;
    bSrc[p] = B + (size_t)(n0 + m) * K + (cs ^ (m & 7)) * 8;
  }

  int aOff[4][2], bOff[NJ][2];
#pragma unroll
  for (int i = 0; i < 4; ++i)
#pragma unroll
    for (int ks = 0; ks < 2; ++ks) {
      const int m = wm * 64 + i * 16 + r16, kb = ks * 4 + g;
      aOff[i][ks] = ((m << 3) + (kb ^ (m & 7))) << 3;
    }
#pragma unroll
  for (int j = 0; j < NJ; ++j)
#pragma unroll
    for (int ks = 0; ks < 2; ++ks) {
      const int n = wn * (16 * NJ) + j * 16 + r16, kb = ks * 4 + g;
      bOff[j][ks] = ((n << 3) + (kb ^ (n & 7))) << 3;
    }

  auto stage = [&](int buf, int kt) {
    const int off = kt * 64;
#pragma unroll
    for (int p = 0; p < ACH; ++p)
      GLDS(aSrc[p] + off, &lA[buf][(t + p * 256) * 8]);
#pragma unroll
    for (int p = 0; p < 4; ++p)
      GLDS(bSrc[p] + off, &lB[buf][(t + p * 256) * 8]);
  };

  f32x4 acc[4][NJ] = {};
  const int nkt = K >> 6;
  stage(0, 0);
  __syncthreads();
  for (int kt = 0; kt < nkt; ++kt) {
    const int cur = kt & 1;
    if (kt + 1 < nkt) stage(cur ^ 1, kt + 1);  // issue-early: hides under MFMA
    const unsigned short* bA = lA[cur];
    const unsigned short* bB = lB[cur];
#pragma unroll
    for (int ks = 0; ks < 2; ++ks) {
      bf16x8 af[4], bfr[NJ];
#pragma unroll
      for (int i = 0; i < 4; ++i) af[i] = *(const bf16x8*)&bA[aOff[i][ks]];
#pragma unroll
      for (int j = 0; j < NJ; ++j) bfr[j] = *(const bf16x8*)&bB[bOff[j][ks]];
#pragma unroll
      for (int i = 0; i < 4; ++i)
#pragma unroll
        for (int j = 0; j < NJ; ++j)
          acc[i][j] = __builtin_amdgcn_mfma_f32_16x16x32_bf16(
              af[i], bfr[j], acc[i][j], 0, 0, 0);
    }
    __syncthreads();  // drains vmcnt: staged kt+1 complete; buf[cur] free
  }

  float bj[NJ];
  if constexpr (MODE == 2 || MODE == 3) {
#pragma unroll
    for (int j = 0; j < NJ; ++j)
      bj[j] = bias[n0 + wn * (16 * NJ) + j * 16 + r16];
  }
#pragma unroll
  for (int i = 0; i < 4; ++i) {
    const int row0 = m0 + wm * 64 + i * 16 + g * 4;
#pragma unroll
    for (int j = 0; j < NJ; ++j) {
      const int colb = n0 + wn * (16 * NJ) + j * 16;
      const int col = colb + r16;
      if constexpr (MODE == 0) {
        if (colb < 2048) {
#pragma unroll
          for (int r = 0; r < 4; ++r)
            outb[(size_t)(row0 + r) * 2048 + col] = f2b(acc[i][j][r]);
        } else {
          const int b = row0 >> 11, s0 = row0 & 2047;
          us4 pk;
          pk.x = f2b(acc[i][j][0]); pk.y = f2b(acc[i][j][1]);
          pk.z = f2b(acc[i][j][2]); pk.w = f2b(acc[i][j][3]);
          *(us4*)&vt[((size_t)b * 1024 + (col - 2048)) * 2048 + s0] = pk;
        }
      } else if constexpr (MODE == 1) {
#pragma unroll
        for (int r = 0; r < 4; ++r) {
          const size_t idx = (size_t)(row0 + r) * N + col;
          outf[idx] = acc[i][j][r] + resid[idx];
        }
      } else if constexpr (MODE == 2) {
#pragma unroll
        for (int r = 0; r < 4; ++r) {
          const float x = acc[i][j][r] + bj[j];
          const float u = x * (0.7978845608028654f + 0.03567740814f * x * x);
          const float e = __builtin_amdgcn_exp2f(u * 2.885390081777927f);
          const float th = 1.0f - 2.0f * __builtin_amdgcn_rcpf(e + 1.0f);
          outb[(size_t)(row0 + r) * N + col] = f2b(0.5f * x * (1.0f + th));
        }
      } else {
#pragma unroll
        for (int r = 0; r < 4; ++r) {
          const size_t idx = (size_t)(row0 + r) * N + col;
          outf[idx] = acc[i][j][r] + bj[j] + resid[idx];
        }
      }
    }
  }
}

// ---------------------------------------------------------------------------
// Flash attention (causal), pair+k-split: block (j, h, z) with z = b*2+half
// handles q-tiles qtA=j, qtB=31-j over HALF the k-range (uniform ~17 steps,
// 1024 blocks = 4/CU). Partial (O, m, l) written to ws; attn_merge combines.
// Swapped QK^T: S^T = mfma(K,Q) -> lane q=lane&15, k=mt*16+(lane>>4)*4+r.
// P^T via XOR-swizzled per-wave LDS (8 KB total); V pre-transposed vt[b][d][s].
// T13 defer-max (THR=44 raw), T5 setprio, cvt_pk packing.
// ---------------------------------------------------------------------------
__global__ void __launch_bounds__(256) attn_kernel(
    const unsigned short* __restrict__ qk, const unsigned short* __restrict__ vt,
    unsigned short* __restrict__ Op, float* __restrict__ mlm,
    float* __restrict__ mll) {
  const int j = blockIdx.x, h = blockIdx.y;
  const int bb = blockIdx.z >> 1, half = blockIdx.z & 1;
  const int t = threadIdx.x, lane = t & 63, w = t >> 6;
  const int r16 = lane & 15, g = lane >> 4;
  __shared__ unsigned short lK[2][64 * 64];
  __shared__ unsigned short lV[2][64 * 64];
  __shared__ unsigned short lP[4][16 * 64];

  const int qtA = j, qtB = 31 - j;
  const int ca = (j + 2) >> 1;        // A k-split point
  const int cb = (33 - j) >> 1;       // B k-split point
  // ranges [alo,ahi) for A-tile steps, [blo,bhi) for B-tile steps
  const int alo = half ? ca : 0, ahi = half ? (qtA + 1) : ca;
  const int blo = half ? cb : 0, bhi = half ? (qtB + 1) : cb;
  const int start = (alo < ahi) ? min(alo, blo) : blo;
  const int kend = bhi;
  const int qrowA = qtA * 64 + w * 16 + r16;
  const int qrowB = qtB * 64 + w * 16 + r16;
  const float CE = 0.18033688011112042f;  // (1/8) * log2(e)

  bf16x8 qfA[2], qfB[2];
  {
    const unsigned short* qa = qk + (size_t)(bb * 2048 + qrowA) * 2048 + h * 64;
    qfA[0] = *(const bf16x8*)(qa + g * 8);
    qfA[1] = *(const bf16x8*)(qa + 32 + g * 8);
    const unsigned short* qb = qk + (size_t)(bb * 2048 + qrowB) * 2048 + h * 64;
    qfB[0] = *(const bf16x8*)(qb + g * 8);
    qfB[1] = *(const bf16x8*)(qb + 32 + g * 8);
  }

  f32x4 accA[4] = {}, accB[4] = {};
  float mA = -3.0e38f, lA_ = 0.0f, mB = -3.0e38f, lB_ = 0.0f;

  auto stage = [&](int buf, int kt) {
    const int k0 = kt * 64;
#pragma unroll
    for (int p = 0; p < 2; ++p) {
      const int ci = t + p * 256;
      const int r = ci >> 3, cs = ci & 7;
      const int cb2 = cs ^ (r & 7);
      GLDS(qk + (size_t)(bb * 2048 + k0 + r) * 2048 + 1024 + h * 64 + cb2 * 8,
           &lK[buf][ci * 8]);
      GLDS(vt + ((size_t)bb * 1024 + h * 64 + r) * 2048 + k0 + cb2 * 8,
           &lV[buf][ci * 8]);
    }
  };

  const int pswz = (r16 & 7) << 3;  // lP XOR swizzle (8-elem granules)

  auto flash_step = [&](const bf16x8* qf, f32x4* accO, float& mrun,
                        float& lrun, int qrow, bool diag, int k0, int cur) {
    f32x4 s[4] = {};
    __builtin_amdgcn_s_setprio(1);
#pragma unroll
    for (int ks = 0; ks < 2; ++ks)
#pragma unroll
      for (int mt = 0; mt < 4; ++mt) {
        const int r = mt * 16 + r16, db = ks * 4 + g;
        const bf16x8 kf =
            *(const bf16x8*)&lK[cur][((r << 3) + (db ^ (r & 7))) << 3];
        s[mt] = __builtin_amdgcn_mfma_f32_16x16x32_bf16(kf, qf[ks], s[mt],
                                                        0, 0, 0);
      }
    __builtin_amdgcn_s_setprio(0);
    if (diag) {
#pragma unroll
      for (int mt = 0; mt < 4; ++mt)
#pragma unroll
        for (int r = 0; r < 4; ++r)
          if (k0 + mt * 16 + g * 4 + r > qrow) s[mt][r] = -3.0e38f;
    }
    float tmax = -3.0e38f;
#pragma unroll
    for (int mt = 0; mt < 4; ++mt)
#pragma unroll
      for (int r = 0; r < 4; ++r) tmax = fmaxf(tmax, s[mt][r]);
    tmax = fmaxf(tmax, __shfl_xor(tmax, 16));
    tmax = fmaxf(tmax, __shfl_xor(tmax, 32));
    // T13 defer-max: only rescale when the running max grew materially
    if (!__all(tmax <= mrun + 44.0f)) {
      const float mnew = fmaxf(mrun, tmax);
      const float fac = __builtin_amdgcn_exp2f((mrun - mnew) * CE);
      lrun *= fac;
      float fr[4];
#pragma unroll
      for (int r = 0; r < 4; ++r) fr[r] = __shfl(fac, g * 4 + r);
#pragma unroll
      for (int nb = 0; nb < 4; ++nb)
#pragma unroll
        for (int r = 0; r < 4; ++r) accO[nb][r] *= fr[r];
      mrun = mnew;
    }
    float pv[4][4];
    float tsum = 0.0f;
#pragma unroll
    for (int mt = 0; mt < 4; ++mt)
#pragma unroll
      for (int r = 0; r < 4; ++r) {
        pv[mt][r] = __builtin_amdgcn_exp2f((s[mt][r] - mrun) * CE);
        tsum += pv[mt][r];
      }
    tsum += __shfl_xor(tsum, 16);
    tsum += __shfl_xor(tsum, 32);
    lrun += tsum;
    // write P^T (per-wave region, XOR-swizzled, cvt_pk packed)
#pragma unroll
    for (int mt = 0; mt < 4; ++mt) {
      u32x2 pk;
      pk.x = cvt_pk_bf16(pv[mt][0], pv[mt][1]);
      pk.y = cvt_pk_bf16(pv[mt][2], pv[mt][3]);
      *(u32x2*)&lP[w][r16 * 64 + ((mt * 16 + g * 4) ^ pswz)] = pk;
    }
    __builtin_amdgcn_s_setprio(1);
#pragma unroll
    for (int ks = 0; ks < 2; ++ks) {
      const bf16x8 pa =
          *(const bf16x8*)&lP[w][r16 * 64 + ((ks * 32 + g * 8) ^ pswz)];
#pragma unroll
      for (int nb = 0; nb < 4; ++nb) {
        const int d = nb * 16 + r16, kb = ks * 4 + g;
        const bf16x8 vf =
            *(const bf16x8*)&lV[cur][((d << 3) + (kb ^ (d & 7))) << 3];
        accO[nb] = __builtin_amdgcn_mfma_f32_16x16x32_bf16(pa, vf, accO[nb],
                                                           0, 0, 0);
      }
    }
    __builtin_amdgcn_s_setprio(0);
  };

  stage(0, start);
  __syncthreads();
  int cur = 0;
  for (int kt = start; kt < kend; ++kt) {
    if (kt + 1 < kend) stage(cur ^ 1, kt + 1);
    if (kt >= blo)
      flash_step(qfB, accB, mB, lB_, qrowB, kt == qtB, kt * 64, cur);
    if (kt >= alo && kt < ahi)
      flash_step(qfA, accA, mA, lA_, qrowA, kt == qtA, kt * 64, cur);
    __syncthreads();  // drains vmcnt: staged kt+1 complete + buf[cur] free
    cur ^= 1;
  }

  // partial epilogue: unnormalized O (bf16) + m,l (f32) per q-row
  const int Rbase = (bb * 16 + h) * 2048;
  auto epi = [&](const f32x4* accO, float mrun, float lrun, int q0) {
#pragma unroll
    for (int nb = 0; nb < 4; ++nb)
#pragma unroll
      for (int r = 0; r < 4; ++r) {
        const int q = q0 + w * 16 + g * 4 + r;
        Op[((size_t)half * 65536 + Rbase + q) * 64 + nb * 16 + r16] =
            f2b(accO[nb][r]);
      }
    if (g == 0) {
      const int q = q0 + w * 16 + r16;
      mlm[half * 65536 + Rbase + q] = mrun;
      mll[half * 65536 + Rbase + q] = lrun;
    }
  };
  epi(accA, mA, lA_, qtA * 64);
  epi(accB, mB, lB_, qtB * 64);
}

// ---------------------------------------------------------------------------
// Merge the two k-half partials: O = (O0*w0 + O1*w1) / (l0*w0 + l1*w1),
// w_h = exp((m_h - m)/8). Writes bf16 ob[(b*2048+q)][h*64+d].
// ---------------------------------------------------------------------------
__global__ void __launch_bounds__(256) attn_merge(
    const unsigned short* __restrict__ Op, const float* __restrict__ mlm,
    const float* __restrict__ mll, unsigned short* __restrict__ obuf) {
  const int R = blockIdx.x * 16 + (threadIdx.x >> 4);
  const int c = (threadIdx.x & 15) * 4;
  const float CE = 0.18033688011112042f;
  const float m0 = mlm[R], m1 = mlm[65536 + R];
  const float l0 = mll[R], l1 = mll[65536 + R];
  const float m = fmaxf(m0, m1);
  const float w0 = __builtin_amdgcn_exp2f((m0 - m) * CE);
  const float w1 = __builtin_amdgcn_exp2f((m1 - m) * CE);
  const float inv = 1.0f / (l0 * w0 + l1 * w1);
  const us4 a = *(const us4*)&Op[(size_t)R * 64 + c];
  const us4 b = *(const us4*)&Op[((size_t)65536 + R) * 64 + c];
  us4 o;
  o.x = f2b((b2f(a.x) * w0 + b2f(b.x) * w1) * inv);
  o.y = f2b((b2f(a.y) * w0 + b2f(b.y) * w1) * inv);
  o.z = f2b((b2f(a.z) * w0 + b2f(b.z) * w1) * inv);
  o.w = f2b((b2f(a.w) * w0 + b2f(b.w) * w1) * inv);
  const int bb = R >> 15, h = (R >> 11) & 15, q = R & 2047;
  *(us4*)&obuf[(size_t)(bb * 2048 + q) * 1024 + h * 64 + c] = o;
}

// ---------------------------------------------------------------------------
extern "C" void kernel_launch(void* const* d_in, const int* in_sizes, int n_in,
                              void* d_out, int out_size, void* d_ws,
                              size_t ws_size, hipStream_t stream) {
  const float* hs   = (const float*)d_in[0];
  const float* Wq   = (const float*)d_in[1];
  const float* Wk   = (const float*)d_in[2];
  const float* Wv   = (const float*)d_in[3];
  const float* Wo   = (const float*)d_in[4];
  const float* W1   = (const float*)d_in[5];
  const float* b1   = (const float*)d_in[6];
  const float* W2   = (const float*)d_in[7];
  const float* b2   = (const float*)d_in[8];
  const float* ln1s = (const float*)d_in[9];
  const float* ln1b = (const float*)d_in[10];
  const float* ln2s = (const float*)d_in[11];
  const float* ln2b = (const float*)d_in[12];
  float* out = (float*)d_out;

  char* ws = (char*)d_ws;
  unsigned short* wqkvT = (unsigned short*)(ws + 0);          //  6 MB [3072][1024]
  unsigned short* woT   = (unsigned short*)(ws + 6291456);    //  2 MB [1024][1024]
  unsigned short* w1T   = (unsigned short*)(ws + 8388608);    //  8 MB [4096][1024]
  unsigned short* w2T   = (unsigned short*)(ws + 16777216);   //  8 MB [1024][4096]
  float*          hid   = (float*)(ws + 25165824);            // 16 MB [4096][1024]
  unsigned short* xb    = (unsigned short*)(ws + 41943040);   //  8 MB [4096][1024]
  char*           big   = ws + 50331648;                      // 32 MB region
  unsigned short* qkb   = (unsigned short*)(big);             // 16 MB [4096][2048]
  unsigned short* vtb   = (unsigned short*)(big + 16777216);  //  8 MB [2][1024][2048]
  unsigned short* ob    = (unsigned short*)(big + 25165824);  //  8 MB [4096][1024]
  unsigned short* h1    = (unsigned short*)(big);             // 32 MB (reuse) [4096][4096]
  char*           att   = ws + 83886080;                      // partials region
  unsigned short* OpB   = (unsigned short*)(att);             // 16.8 MB [2][65536][64]
  float*          mlmB  = (float*)(att + 16777216);           // 512 KB [2][65536]
  float*          mllB  = (float*)(att + 17301504);           // 512 KB [2][65536]

  // weights -> bf16, transposed
  transpose_w<<<dim3(32, 32), 256, 0, stream>>>(Wq, wqkvT, 1024, 1024);
  transpose_w<<<dim3(32, 32), 256, 0, stream>>>(Wk, wqkvT + 1024 * 1024, 1024, 1024);
  transpose_w<<<dim3(32, 32), 256, 0, stream>>>(Wv, wqkvT + 2 * 1024 * 1024, 1024, 1024);
  transpose_w<<<dim3(32, 32), 256, 0, stream>>>(Wo, woT, 1024, 1024);
  transpose_w<<<dim3(128, 32), 256, 0, stream>>>(W1, w1T, 1024, 4096);
  transpose_w<<<dim3(32, 128), 256, 0, stream>>>(W2, w2T, 4096, 1024);

  // LN1
  ln_kernel<<<4096, 256, 0, stream>>>(hs, ln1s, ln1b, xb);
  // QKV projection (fused, V written transposed)
  gemm_bt<0, 128><<<dim3(32, 24), 256, 0, stream>>>(xb, wqkvT, 1024, 3072,
                                                    nullptr, qkb, nullptr, nullptr, vtb);
  // attention: paired q-tiles, split k-range (1024 uniform blocks) + merge
  attn_kernel<<<dim3(16, 16, 4), 256, 0, stream>>>(qkb, vtb, OpB, mlmB, mllB);
  attn_merge<<<4096, 256, 0, stream>>>(OpB, mlmB, mllB, ob);
  // output projection + residual (BM=64 -> 512 blocks)
  gemm_bt<1, 64><<<dim3(64, 8), 256, 0, stream>>>(ob, woT, 1024, 1024,
                                                  hid, nullptr, nullptr, hs, nullptr);
  // LN2
  ln_kernel<<<4096, 256, 0, stream>>>(hid, ln2s, ln2b, xb);
  // FFN up + GELU (tanh approx)
  gemm_bt<2, 128><<<dim3(32, 32), 256, 0, stream>>>(xb, w1T, 1024, 4096,
                                                    nullptr, h1, b1, nullptr, nullptr);
  // FFN down + bias + residual -> out (BM=64 -> 512 blocks)
  gemm_bt<3, 64><<<dim3(64, 8), 256, 0, stream>>>(h1, w2T, 4096, 1024,
                                                  out, nullptr, b2, hid, nullptr);
}

// Round 5
// 247.020 us; speedup vs baseline: 1.0431x; 1.0431x over previous
//
#include <hip/hip_runtime.h>
#include <math.h>

using bf16x8 = __attribute__((ext_vector_type(8))) short;
using f32x4  = __attribute__((ext_vector_type(4))) float;

struct __align__(8) us4 { unsigned short x, y, z, w; };

__device__ __forceinline__ unsigned short f2b(float f) {
  union { float f; unsigned u; } v; v.f = f;
  unsigned r = v.u + 0x7FFFu + ((v.u >> 16) & 1u);
  return (unsigned short)(r >> 16);
}

#define GLDS(g, l) __builtin_amdgcn_global_load_lds(                        \
    (const __attribute__((address_space(1))) void*)(g),                    \
    (__attribute__((address_space(3))) void*)(l), 16, 0, 0)

// ---------------------------------------------------------------------------
// Weight transpose + fp32->bf16 convert:  src[K][N] (f32) -> dst[N][K] (bf16)
// ---------------------------------------------------------------------------
__global__ void __launch_bounds__(256) transpose_w(
    const float* __restrict__ src, unsigned short* __restrict__ dst,
    int K, int N) {
  __shared__ float tile[32][33];
  const int n0 = blockIdx.x * 32, k0 = blockIdx.y * 32;
  const int tx = threadIdx.x & 31, ty = threadIdx.x >> 5;  // 32 x 8
#pragma unroll
  for (int i = 0; i < 32; i += 8)
    tile[ty + i][tx] = src[(size_t)(k0 + ty + i) * N + n0 + tx];
  __syncthreads();
#pragma unroll
  for (int i = 0; i < 32; i += 8)
    dst[(size_t)(n0 + ty + i) * K + k0 + tx] = f2b(tile[tx][ty + i]);
}

// ---------------------------------------------------------------------------
// LayerNorm over last dim (1024), fp32 in -> bf16 out
// ---------------------------------------------------------------------------
__global__ void __launch_bounds__(256) ln_kernel(
    const float* __restrict__ in, const float* __restrict__ scale,
    const float* __restrict__ shift, unsigned short* __restrict__ out) {
  const int row = blockIdx.x, t = threadIdx.x;
  const float4 v = ((const float4*)(in + (size_t)row * 1024))[t];
  float s  = v.x + v.y + v.z + v.w;
  float s2 = v.x * v.x + v.y * v.y + v.z * v.z + v.w * v.w;
#pragma unroll
  for (int off = 32; off; off >>= 1) {
    s  += __shfl_xor(s,  off);
    s2 += __shfl_xor(s2, off);
  }
  __shared__ float red[8];
  const int w = t >> 6, lane = t & 63;
  if (!lane) { red[w] = s; red[4 + w] = s2; }
  __syncthreads();
  s  = red[0] + red[1] + red[2] + red[3];
  s2 = red[4] + red[5] + red[6] + red[7];
  const float mean = s * (1.0f / 1024.0f);
  const float var  = s2 * (1.0f / 1024.0f) - mean * mean;
  const float rstd = rsqrtf(var + 1e-5f);
  const float4 sc = ((const float4*)scale)[t];
  const float4 sh = ((const float4*)shift)[t];
  us4 o;
  o.x = f2b((v.x - mean) * rstd * sc.x + sh.x);
  o.y = f2b((v.y - mean) * rstd * sc.y + sh.y);
  o.z = f2b((v.z - mean) * rstd * sc.z + sh.z);
  o.w = f2b((v.w - mean) * rstd * sc.w + sh.w);
  ((us4*)(out + (size_t)row * 1024))[t] = o;
}

// ---------------------------------------------------------------------------
// 256x256 GEMM, 8 waves (2M x 4N), BK=64, counted-vmcnt pipeline (T3+T4).
// Raw s_barrier (no vmcnt drain) + s_waitcnt vmcnt(8): the 8 global_load_lds
// for the NEXT K-tile stay in flight across the barrier; we only wait for
// the PREVIOUS tile's 8 loads. sched_barrier(0) pins ordering (rule #18/#21).
// LDS chunk layout: chunk (row, kb) at index row*8+(kb^(row&7)), swizzle
// applied to the global source column so GLDS dest stays linear (m173).
// MODE 0: qkv split -> qk bf16 [4096][2048] + vt bf16 [2][1024][2048] (V^T)
// MODE 2: out_bf16 = gelu_tanh(acc + bias)
// ---------------------------------------------------------------------------
template <int MODE>
__global__ void __launch_bounds__(512, 2) gemm256(
    const unsigned short* __restrict__ A, const unsigned short* __restrict__ B,
    int K, int N, unsigned short* __restrict__ outb,
    const float* __restrict__ bias, unsigned short* __restrict__ vt) {
  __shared__ unsigned short lA[2][256 * 64];
  __shared__ unsigned short lB[2][256 * 64];
  const int t = threadIdx.x, lane = t & 63;
  const int w = t >> 6, wm = w >> 2, wn = w & 3;
  const int r16 = lane & 15, g = lane >> 4;
  const int m0 = blockIdx.x * 256, n0 = blockIdx.y * 256;

  // staging sources: 4 A-chunks + 4 B-chunks per thread per K-tile
  const unsigned short* aSrc[4];
  const unsigned short* bSrc[4];
#pragma unroll
  for (int p = 0; p < 4; ++p) {
    const int ci = t + p * 512, r = ci >> 3, cs = ci & 7;
    aSrc[p] = A + (size_t)(m0 + r) * K + (cs ^ (r & 7)) * 8;
    bSrc[p] = B + (size_t)(n0 + r) * K + (cs ^ (r & 7)) * 8;
  }
  // fragment LDS element-offsets
  int aOff[8][2], bOff[4][2];
#pragma unroll
  for (int i = 0; i < 8; ++i)
#pragma unroll
    for (int ks = 0; ks < 2; ++ks) {
      const int m = wm * 128 + i * 16 + r16, kb = ks * 4 + g;
      aOff[i][ks] = ((m << 3) + (kb ^ (m & 7))) << 3;
    }
#pragma unroll
  for (int j = 0; j < 4; ++j)
#pragma unroll
    for (int ks = 0; ks < 2; ++ks) {
      const int n = wn * 64 + j * 16 + r16, kb = ks * 4 + g;
      bOff[j][ks] = ((n << 3) + (kb ^ (n & 7))) << 3;
    }

  auto stage = [&](int buf, int kt) {
    const int off = kt * 64;
#pragma unroll
    for (int p = 0; p < 4; ++p) {
      GLDS(aSrc[p] + off, &lA[buf][(t + p * 512) * 8]);
      GLDS(bSrc[p] + off, &lB[buf][(t + p * 512) * 8]);
    }
  };

  f32x4 acc[8][4] = {};
  const int nkt = K >> 6;
  stage(0, 0);
  for (int kt = 0; kt < nkt; ++kt) {
    const int cur = kt & 1;
    if (kt + 1 < nkt) {
      stage(cur ^ 1, kt + 1);  // 8 loads into buf[cur^1], left in flight
      asm volatile("s_waitcnt vmcnt(8)" ::: "memory");  // buf[cur] landed
    } else {
      asm volatile("s_waitcnt vmcnt(0)" ::: "memory");
    }
    __builtin_amdgcn_s_barrier();          // all waves: buf[cur] staged
    __builtin_amdgcn_sched_barrier(0);     // no LDS reads hoisted above
    const unsigned short* bA = lA[cur];
    const unsigned short* bB = lB[cur];
#pragma unroll
    for (int ks = 0; ks < 2; ++ks) {
      bf16x8 af[8], bfr[4];
#pragma unroll
      for (int i = 0; i < 8; ++i) af[i] = *(const bf16x8*)&bA[aOff[i][ks]];
#pragma unroll
      for (int j = 0; j < 4; ++j) bfr[j] = *(const bf16x8*)&bB[bOff[j][ks]];
      __builtin_amdgcn_s_setprio(1);
#pragma unroll
      for (int i = 0; i < 8; ++i)
#pragma unroll
        for (int j = 0; j < 4; ++j)
          acc[i][j] = __builtin_amdgcn_mfma_f32_16x16x32_bf16(
              af[i], bfr[j], acc[i][j], 0, 0, 0);
      __builtin_amdgcn_s_setprio(0);
    }
    __builtin_amdgcn_sched_barrier(0);     // no next-iter GLDS hoisted above
    __builtin_amdgcn_s_barrier();          // all waves done reading buf[cur]
  }

  // epilogue: C/D layout col = lane&15, row = (lane>>4)*4 + reg
  float bj[4];
  if constexpr (MODE == 2) {
#pragma unroll
    for (int j = 0; j < 4; ++j) bj[j] = bias[n0 + wn * 64 + j * 16 + r16];
  }
#pragma unroll
  for (int i = 0; i < 8; ++i) {
    const int row0 = m0 + wm * 128 + i * 16 + g * 4;
#pragma unroll
    for (int j = 0; j < 4; ++j) {
      const int colb = n0 + wn * 64 + j * 16;
      const int col = colb + r16;
      if constexpr (MODE == 0) {
        if (colb < 2048) {
#pragma unroll
          for (int r = 0; r < 4; ++r)
            outb[(size_t)(row0 + r) * 2048 + col] = f2b(acc[i][j][r]);
        } else {
          const int b = row0 >> 11, s0 = row0 & 2047;
          us4 pk;
          pk.x = f2b(acc[i][j][0]); pk.y = f2b(acc[i][j][1]);
          pk.z = f2b(acc[i][j][2]); pk.w = f2b(acc[i][j][3]);
          *(us4*)&vt[((size_t)b * 1024 + (col - 2048)) * 2048 + s0] = pk;
        }
      } else {
#pragma unroll
        for (int r = 0; r < 4; ++r) {
          const float x = acc[i][j][r] + bj[j];
          const float u = x * (0.7978845608028654f + 0.03567740814f * x * x);
          const float e = __builtin_amdgcn_exp2f(u * 2.885390081777927f);
          const float th = 1.0f - 2.0f * __builtin_amdgcn_rcpf(e + 1.0f);
          outb[(size_t)(row0 + r) * N + col] = f2b(0.5f * x * (1.0f + th));
        }
      }
    }
  }
}

// ---------------------------------------------------------------------------
// GEMM: C[M,N] = A[M,K](bf16) * B^T with B stored as [N,K](bf16).
// BMx128 tile, BK=64, 4 waves. Double-buffered LDS, single barrier per
// K-step. Used for the N=1024 GEMMs (Wo, FFN-down) where 256-wide tiles
// would under-fill the grid.
// MODE 1: out_f32 = acc + resid
// MODE 3: out_f32 = acc + bias + resid
// ---------------------------------------------------------------------------
template <int MODE, int BM>
__global__ void __launch_bounds__(256) gemm_bt(
    const unsigned short* __restrict__ A, const unsigned short* __restrict__ B,
    int K, int N,
    float* __restrict__ outf, const float* __restrict__ bias,
    const float* __restrict__ resid) {
  constexpr int WN = (BM == 128) ? 2 : 4;   // waves along N
  constexpr int NJ = 128 / (16 * WN);       // N-fragments per wave
  constexpr int ACH = BM / 32;              // A staging passes
  __shared__ unsigned short lA[2][BM * 64];
  __shared__ unsigned short lB[2][128 * 64];
  const int t = threadIdx.x, lane = t & 63;
  const int w = t >> 6, wm = w / WN, wn = w % WN;
  const int r16 = lane & 15, g = lane >> 4;
  const int m0 = blockIdx.x * BM, n0 = blockIdx.y * 128;

  const unsigned short* aSrc[ACH];
  const unsigned short* bSrc[4];
#pragma unroll
  for (int p = 0; p < ACH; ++p) {
    const int ci = t + p * 256, m = ci >> 3, cs = ci & 7;
    aSrc[p] = A + (size_t)(m0 + m) * K + (cs ^ (m & 7)) * 8;
  }
#pragma unroll
  for (int p = 0; p < 4; ++p) {
    const int ci = t + p * 256, m = ci >> 3, cs = ci & 7;
    bSrc[p] = B + (size_t)(n0 + m) * K + (cs ^ (m & 7)) * 8;
  }

  int aOff[4][2], bOff[NJ][2];
#pragma unroll
  for (int i = 0; i < 4; ++i)
#pragma unroll
    for (int ks = 0; ks < 2; ++ks) {
      const int m = wm * 64 + i * 16 + r16, kb = ks * 4 + g;
      aOff[i][ks] = ((m << 3) + (kb ^ (m & 7))) << 3;
    }
#pragma unroll
  for (int j = 0; j < NJ; ++j)
#pragma unroll
    for (int ks = 0; ks < 2; ++ks) {
      const int n = wn * (16 * NJ) + j * 16 + r16, kb = ks * 4 + g;
      bOff[j][ks] = ((n << 3) + (kb ^ (n & 7))) << 3;
    }

  auto stage = [&](int buf, int kt) {
    const int off = kt * 64;
#pragma unroll
    for (int p = 0; p < ACH; ++p)
      GLDS(aSrc[p] + off, &lA[buf][(t + p * 256) * 8]);
#pragma unroll
    for (int p = 0; p < 4; ++p)
      GLDS(bSrc[p] + off, &lB[buf][(t + p * 256) * 8]);
  };

  f32x4 acc[4][NJ] = {};
  const int nkt = K >> 6;
  stage(0, 0);
  __syncthreads();
  for (int kt = 0; kt < nkt; ++kt) {
    const int cur = kt & 1;
    if (kt + 1 < nkt) stage(cur ^ 1, kt + 1);  // issue-early: hides under MFMA
    const unsigned short* bA = lA[cur];
    const unsigned short* bB = lB[cur];
#pragma unroll
    for (int ks = 0; ks < 2; ++ks) {
      bf16x8 af[4], bfr[NJ];
#pragma unroll
      for (int i = 0; i < 4; ++i) af[i] = *(const bf16x8*)&bA[aOff[i][ks]];
#pragma unroll
      for (int j = 0; j < NJ; ++j) bfr[j] = *(const bf16x8*)&bB[bOff[j][ks]];
#pragma unroll
      for (int i = 0; i < 4; ++i)
#pragma unroll
        for (int j = 0; j < NJ; ++j)
          acc[i][j] = __builtin_amdgcn_mfma_f32_16x16x32_bf16(
              af[i], bfr[j], acc[i][j], 0, 0, 0);
    }
    __syncthreads();  // drains vmcnt: staged kt+1 complete; buf[cur] free
  }

  float bj[NJ];
  if constexpr (MODE == 3) {
#pragma unroll
    for (int j = 0; j < NJ; ++j)
      bj[j] = bias[n0 + wn * (16 * NJ) + j * 16 + r16];
  }
#pragma unroll
  for (int i = 0; i < 4; ++i) {
    const int row0 = m0 + wm * 64 + i * 16 + g * 4;
#pragma unroll
    for (int j = 0; j < NJ; ++j) {
      const int col = n0 + wn * (16 * NJ) + j * 16 + r16;
      if constexpr (MODE == 1) {
#pragma unroll
        for (int r = 0; r < 4; ++r) {
          const size_t idx = (size_t)(row0 + r) * N + col;
          outf[idx] = acc[i][j][r] + resid[idx];
        }
      } else {
#pragma unroll
        for (int r = 0; r < 4; ++r) {
          const size_t idx = (size_t)(row0 + r) * N + col;
          outf[idx] = acc[i][j][r] + bj[j] + resid[idx];
        }
      }
    }
  }
}

// ---------------------------------------------------------------------------
// Flash attention (causal), load-balanced: block j handles q-tiles j and 31-j
// (33 k-tile compute-steps for every block), sharing one K/V staging pass.
// Grid (16, h=16, b=2), 256 threads (4 waves), K/V double-buffered in LDS
// with a single barrier per k-tile step (stage overlaps compute).
// Swapped QK^T: S^T = mfma(K,Q) -> lane holds q=lane&15, k=mt*16+(lane>>4)*4+r.
// P^T goes through per-wave LDS; V comes pre-transposed as vt[b][d][s].
// (round-3 version, reverted after the k-split regression of round 4)
// ---------------------------------------------------------------------------
__global__ void __launch_bounds__(256) attn_kernel(
    const unsigned short* __restrict__ qk, const unsigned short* __restrict__ vt,
    unsigned short* __restrict__ obuf) {
  const int j = blockIdx.x, h = blockIdx.y, bb = blockIdx.z;
  const int t = threadIdx.x, lane = t & 63, w = t >> 6;
  const int r16 = lane & 15, g = lane >> 4;
  __shared__ unsigned short lK[2][64 * 64];
  __shared__ unsigned short lV[2][64 * 64];
  __shared__ unsigned short lP[4][16 * 72];

  const int qtA = j, qtB = 31 - j;   // qtA <= qtB
  const int ktmax = qtB;
  const int qrowA = qtA * 64 + w * 16 + r16;
  const int qrowB = qtB * 64 + w * 16 + r16;
  const float CE = 0.18033688011112042f;  // (1/8) * log2(e)

  bf16x8 qfA[2], qfB[2];
  {
    const unsigned short* qa =
        qk + (size_t)(bb * 2048 + qrowA) * 2048 + h * 64;
    qfA[0] = *(const bf16x8*)(qa + g * 8);
    qfA[1] = *(const bf16x8*)(qa + 32 + g * 8);
    const unsigned short* qb =
        qk + (size_t)(bb * 2048 + qrowB) * 2048 + h * 64;
    qfB[0] = *(const bf16x8*)(qb + g * 8);
    qfB[1] = *(const bf16x8*)(qb + 32 + g * 8);
  }

  f32x4 accA[4] = {}, accB[4] = {};
  float mA = -3.0e38f, lA_ = 0.0f, mB = -3.0e38f, lB_ = 0.0f;

  auto stage = [&](int buf, int kt) {
    const int k0 = kt * 64;
#pragma unroll
    for (int p = 0; p < 2; ++p) {
      const int ci = t + p * 256;
      const int r = ci >> 3, cs = ci & 7;
      const int cb = cs ^ (r & 7);
      GLDS(qk + (size_t)(bb * 2048 + k0 + r) * 2048 + 1024 + h * 64 + cb * 8,
           &lK[buf][ci * 8]);
      GLDS(vt + ((size_t)bb * 1024 + h * 64 + r) * 2048 + k0 + cb * 8,
           &lV[buf][ci * 8]);
    }
  };

  auto flash_step = [&](const bf16x8* qf, f32x4* accO, float& mrun,
                        float& lrun, int qrow, bool diag, int k0, int cur) {
    f32x4 s[4] = {};
#pragma unroll
    for (int ks = 0; ks < 2; ++ks)
#pragma unroll
      for (int mt = 0; mt < 4; ++mt) {
        const int r = mt * 16 + r16, db = ks * 4 + g;
        const bf16x8 kf =
            *(const bf16x8*)&lK[cur][((r << 3) + (db ^ (r & 7))) << 3];
        s[mt] = __builtin_amdgcn_mfma_f32_16x16x32_bf16(kf, qf[ks], s[mt],
                                                        0, 0, 0);
      }
    if (diag) {
#pragma unroll
      for (int mt = 0; mt < 4; ++mt)
#pragma unroll
        for (int r = 0; r < 4; ++r)
          if (k0 + mt * 16 + g * 4 + r > qrow) s[mt][r] = -3.0e38f;
    }
    float tmax = -3.0e38f;
#pragma unroll
    for (int mt = 0; mt < 4; ++mt)
#pragma unroll
      for (int r = 0; r < 4; ++r) tmax = fmaxf(tmax, s[mt][r]);
    tmax = fmaxf(tmax, __shfl_xor(tmax, 16));
    tmax = fmaxf(tmax, __shfl_xor(tmax, 32));
    const float mnew = fmaxf(mrun, tmax);
    const float fac = __builtin_amdgcn_exp2f((mrun - mnew) * CE);
    float pv[4][4];
    float tsum = 0.0f;
#pragma unroll
    for (int mt = 0; mt < 4; ++mt)
#pragma unroll
      for (int r = 0; r < 4; ++r) {
        pv[mt][r] = __builtin_amdgcn_exp2f((s[mt][r] - mnew) * CE);
        tsum += pv[mt][r];
      }
    tsum += __shfl_xor(tsum, 16);
    tsum += __shfl_xor(tsum, 32);
    lrun = lrun * fac + tsum;
    mrun = mnew;
#pragma unroll
    for (int mt = 0; mt < 4; ++mt) {
      us4 pk;
      pk.x = f2b(pv[mt][0]); pk.y = f2b(pv[mt][1]);
      pk.z = f2b(pv[mt][2]); pk.w = f2b(pv[mt][3]);
      *(us4*)&lP[w][r16 * 72 + mt * 16 + g * 4] = pk;
    }
    float fr[4];
#pragma unroll
    for (int r = 0; r < 4; ++r) fr[r] = __shfl(fac, g * 4 + r);
#pragma unroll
    for (int nb = 0; nb < 4; ++nb)
#pragma unroll
      for (int r = 0; r < 4; ++r) accO[nb][r] *= fr[r];
#pragma unroll
    for (int ks = 0; ks < 2; ++ks) {
      const bf16x8 pa = *(const bf16x8*)&lP[w][r16 * 72 + ks * 32 + g * 8];
#pragma unroll
      for (int nb = 0; nb < 4; ++nb) {
        const int d = nb * 16 + r16, kb = ks * 4 + g;
        const bf16x8 vf =
            *(const bf16x8*)&lV[cur][((d << 3) + (kb ^ (d & 7))) << 3];
        accO[nb] = __builtin_amdgcn_mfma_f32_16x16x32_bf16(pa, vf, accO[nb],
                                                           0, 0, 0);
      }
    }
  };

  stage(0, 0);
  __syncthreads();
  int cur = 0;
  for (int kt = 0; kt <= ktmax; ++kt) {
    if (kt < ktmax) stage(cur ^ 1, kt + 1);
    flash_step(qfB, accB, mB, lB_, qrowB, kt == qtB, kt * 64, cur);
    if (kt <= qtA)
      flash_step(qfA, accA, mA, lA_, qrowA, kt == qtA, kt * 64, cur);
    __syncthreads();  // drains vmcnt: staged kt+1 complete + lK/lV[cur] free
    cur ^= 1;
  }

  auto epilogue = [&](const f32x4* accO, float lrun, int q0) {
    const float li = 1.0f / lrun;
    float lr_[4];
#pragma unroll
    for (int r = 0; r < 4; ++r) lr_[r] = __shfl(li, g * 4 + r);
#pragma unroll
    for (int nb = 0; nb < 4; ++nb)
#pragma unroll
      for (int r = 0; r < 4; ++r) {
        const int row = bb * 2048 + q0 + w * 16 + g * 4 + r;
        const int col = h * 64 + nb * 16 + r16;
        obuf[(size_t)row * 1024 + col] = f2b(accO[nb][r] * lr_[r]);
      }
  };
  epilogue(accA, lA_, qtA * 64);
  epilogue(accB, lB_, qtB * 64);
}

// ---------------------------------------------------------------------------
extern "C" void kernel_launch(void* const* d_in, const int* in_sizes, int n_in,
                              void* d_out, int out_size, void* d_ws,
                              size_t ws_size, hipStream_t stream) {
  const float* hs   = (const float*)d_in[0];
  const float* Wq   = (const float*)d_in[1];
  const float* Wk   = (const float*)d_in[2];
  const float* Wv   = (const float*)d_in[3];
  const float* Wo   = (const float*)d_in[4];
  const float* W1   = (const float*)d_in[5];
  const float* b1   = (const float*)d_in[6];
  const float* W2   = (const float*)d_in[7];
  const float* b2   = (const float*)d_in[8];
  const float* ln1s = (const float*)d_in[9];
  const float* ln1b = (const float*)d_in[10];
  const float* ln2s = (const float*)d_in[11];
  const float* ln2b = (const float*)d_in[12];
  float* out = (float*)d_out;

  char* ws = (char*)d_ws;
  unsigned short* wqkvT = (unsigned short*)(ws + 0);          //  6 MB [3072][1024]
  unsigned short* woT   = (unsigned short*)(ws + 6291456);    //  2 MB [1024][1024]
  unsigned short* w1T   = (unsigned short*)(ws + 8388608);    //  8 MB [4096][1024]
  unsigned short* w2T   = (unsigned short*)(ws + 16777216);   //  8 MB [1024][4096]
  float*          hid   = (float*)(ws + 25165824);            // 16 MB [4096][1024]
  unsigned short* xb    = (unsigned short*)(ws + 41943040);   //  8 MB [4096][1024]
  char*           big   = ws + 50331648;                      // 32 MB region
  unsigned short* qkb   = (unsigned short*)(big);             // 16 MB [4096][2048]
  unsigned short* vtb   = (unsigned short*)(big + 16777216);  //  8 MB [2][1024][2048]
  unsigned short* ob    = (unsigned short*)(big + 25165824);  //  8 MB [4096][1024]
  unsigned short* h1    = (unsigned short*)(big);             // 32 MB (reuse) [4096][4096]

  // weights -> bf16, transposed
  transpose_w<<<dim3(32, 32), 256, 0, stream>>>(Wq, wqkvT, 1024, 1024);
  transpose_w<<<dim3(32, 32), 256, 0, stream>>>(Wk, wqkvT + 1024 * 1024, 1024, 1024);
  transpose_w<<<dim3(32, 32), 256, 0, stream>>>(Wv, wqkvT + 2 * 1024 * 1024, 1024, 1024);
  transpose_w<<<dim3(32, 32), 256, 0, stream>>>(Wo, woT, 1024, 1024);
  transpose_w<<<dim3(128, 32), 256, 0, stream>>>(W1, w1T, 1024, 4096);
  transpose_w<<<dim3(32, 128), 256, 0, stream>>>(W2, w2T, 4096, 1024);

  // LN1
  ln_kernel<<<4096, 256, 0, stream>>>(hs, ln1s, ln1b, xb);
  // QKV projection (256^2 counted-vmcnt pipeline; V written transposed)
  gemm256<0><<<dim3(16, 12), 512, 0, stream>>>(xb, wqkvT, 1024, 3072,
                                               qkb, nullptr, vtb);
  // attention (load-balanced paired q-tiles)
  attn_kernel<<<dim3(16, 16, 2), 256, 0, stream>>>(qkb, vtb, ob);
  // output projection + residual (BM=64 -> 512 blocks)
  gemm_bt<1, 64><<<dim3(64, 8), 256, 0, stream>>>(ob, woT, 1024, 1024,
                                                  hid, nullptr, hs);
  // LN2
  ln_kernel<<<4096, 256, 0, stream>>>(hid, ln2s, ln2b, xb);
  // FFN up + GELU (tanh approx), 256^2 counted-vmcnt pipeline
  gemm256<2><<<dim3(16, 16), 512, 0, stream>>>(xb, w1T, 1024, 4096,
                                               h1, b1, nullptr);
  // FFN down + bias + residual -> out (BM=64 -> 512 blocks)
  gemm_bt<3, 64><<<dim3(64, 8), 256, 0, stream>>>(h1, w2T, 4096, 1024,
                                                  out, b2, hid);
}

// Round 6
// 242.718 us; speedup vs baseline: 1.0616x; 1.0177x over previous
//
#include <hip/hip_runtime.h>
#include <math.h>

using bf16x8 = __attribute__((ext_vector_type(8))) short;
using f32x4  = __attribute__((ext_vector_type(4))) float;

struct __align__(8) us4 { unsigned short x, y, z, w; };
struct __align__(8) u32x2 { unsigned int x, y; };

__device__ __forceinline__ unsigned short f2b(float f) {
  union { float f; unsigned u; } v; v.f = f;
  unsigned r = v.u + 0x7FFFu + ((v.u >> 16) & 1u);
  return (unsigned short)(r >> 16);
}
__device__ __forceinline__ unsigned int cvt_pk_bf16(float lo, float hi) {
  unsigned int d;
  asm("v_cvt_pk_bf16_f32 %0, %1, %2" : "=v"(d) : "v"(lo), "v"(hi));
  return d;
}

#define GLDS(g, l) __builtin_amdgcn_global_load_lds(                        \
    (const __attribute__((address_space(1))) void*)(g),                    \
    (__attribute__((address_space(3))) void*)(l), 16, 0, 0)

// ---------------------------------------------------------------------------
// Weight transpose + fp32->bf16 convert:  src[K][N] (f32) -> dst[N][K] (bf16)
// ---------------------------------------------------------------------------
__global__ void __launch_bounds__(256) transpose_w(
    const float* __restrict__ src, unsigned short* __restrict__ dst,
    int K, int N) {
  __shared__ float tile[32][33];
  const int n0 = blockIdx.x * 32, k0 = blockIdx.y * 32;
  const int tx = threadIdx.x & 31, ty = threadIdx.x >> 5;  // 32 x 8
#pragma unroll
  for (int i = 0; i < 32; i += 8)
    tile[ty + i][tx] = src[(size_t)(k0 + ty + i) * N + n0 + tx];
  __syncthreads();
#pragma unroll
  for (int i = 0; i < 32; i += 8)
    dst[(size_t)(n0 + ty + i) * K + k0 + tx] = f2b(tile[tx][ty + i]);
}

// ---------------------------------------------------------------------------
// LayerNorm over last dim (1024), fp32 in -> bf16 out
// ---------------------------------------------------------------------------
__global__ void __launch_bounds__(256) ln_kernel(
    const float* __restrict__ in, const float* __restrict__ scale,
    const float* __restrict__ shift, unsigned short* __restrict__ out) {
  const int row = blockIdx.x, t = threadIdx.x;
  const float4 v = ((const float4*)(in + (size_t)row * 1024))[t];
  float s  = v.x + v.y + v.z + v.w;
  float s2 = v.x * v.x + v.y * v.y + v.z * v.z + v.w * v.w;
#pragma unroll
  for (int off = 32; off; off >>= 1) {
    s  += __shfl_xor(s,  off);
    s2 += __shfl_xor(s2, off);
  }
  __shared__ float red[8];
  const int w = t >> 6, lane = t & 63;
  if (!lane) { red[w] = s; red[4 + w] = s2; }
  __syncthreads();
  s  = red[0] + red[1] + red[2] + red[3];
  s2 = red[4] + red[5] + red[6] + red[7];
  const float mean = s * (1.0f / 1024.0f);
  const float var  = s2 * (1.0f / 1024.0f) - mean * mean;
  const float rstd = rsqrtf(var + 1e-5f);
  const float4 sc = ((const float4*)scale)[t];
  const float4 sh = ((const float4*)shift)[t];
  us4 o;
  o.x = f2b((v.x - mean) * rstd * sc.x + sh.x);
  o.y = f2b((v.y - mean) * rstd * sc.y + sh.y);
  o.z = f2b((v.z - mean) * rstd * sc.z + sh.z);
  o.w = f2b((v.w - mean) * rstd * sc.w + sh.w);
  ((us4*)(out + (size_t)row * 1024))[t] = o;
}

// ---------------------------------------------------------------------------
// 256x256 GEMM, 8 waves (2M x 4N), BK=64, counted-vmcnt pipeline (T3+T4).
// MODE 0: qkv split -> qk bf16 [4096][2048] + vt bf16 [2][1024][2048] (V^T)
// MODE 2: out_bf16 = gelu_tanh(acc + bias)
// ---------------------------------------------------------------------------
template <int MODE>
__global__ void __launch_bounds__(512, 2) gemm256(
    const unsigned short* __restrict__ A, const unsigned short* __restrict__ B,
    int K, int N, unsigned short* __restrict__ outb,
    const float* __restrict__ bias, unsigned short* __restrict__ vt) {
  __shared__ unsigned short lA[2][256 * 64];
  __shared__ unsigned short lB[2][256 * 64];
  const int t = threadIdx.x, lane = t & 63;
  const int w = t >> 6, wm = w >> 2, wn = w & 3;
  const int r16 = lane & 15, g = lane >> 4;
  const int m0 = blockIdx.x * 256, n0 = blockIdx.y * 256;

  const unsigned short* aSrc[4];
  const unsigned short* bSrc[4];
#pragma unroll
  for (int p = 0; p < 4; ++p) {
    const int ci = t + p * 512, r = ci >> 3, cs = ci & 7;
    aSrc[p] = A + (size_t)(m0 + r) * K + (cs ^ (r & 7)) * 8;
    bSrc[p] = B + (size_t)(n0 + r) * K + (cs ^ (r & 7)) * 8;
  }
  int aOff[8][2], bOff[4][2];
#pragma unroll
  for (int i = 0; i < 8; ++i)
#pragma unroll
    for (int ks = 0; ks < 2; ++ks) {
      const int m = wm * 128 + i * 16 + r16, kb = ks * 4 + g;
      aOff[i][ks] = ((m << 3) + (kb ^ (m & 7))) << 3;
    }
#pragma unroll
  for (int j = 0; j < 4; ++j)
#pragma unroll
    for (int ks = 0; ks < 2; ++ks) {
      const int n = wn * 64 + j * 16 + r16, kb = ks * 4 + g;
      bOff[j][ks] = ((n << 3) + (kb ^ (n & 7))) << 3;
    }

  auto stage = [&](int buf, int kt) {
    const int off = kt * 64;
#pragma unroll
    for (int p = 0; p < 4; ++p) {
      GLDS(aSrc[p] + off, &lA[buf][(t + p * 512) * 8]);
      GLDS(bSrc[p] + off, &lB[buf][(t + p * 512) * 8]);
    }
  };

  f32x4 acc[8][4] = {};
  const int nkt = K >> 6;
  stage(0, 0);
  for (int kt = 0; kt < nkt; ++kt) {
    const int cur = kt & 1;
    if (kt + 1 < nkt) {
      stage(cur ^ 1, kt + 1);  // 8 loads into buf[cur^1], left in flight
      asm volatile("s_waitcnt vmcnt(8)" ::: "memory");  // buf[cur] landed
    } else {
      asm volatile("s_waitcnt vmcnt(0)" ::: "memory");
    }
    __builtin_amdgcn_s_barrier();          // all waves: buf[cur] staged
    __builtin_amdgcn_sched_barrier(0);     // no LDS reads hoisted above
    const unsigned short* bA = lA[cur];
    const unsigned short* bB = lB[cur];
#pragma unroll
    for (int ks = 0; ks < 2; ++ks) {
      bf16x8 af[8], bfr[4];
#pragma unroll
      for (int i = 0; i < 8; ++i) af[i] = *(const bf16x8*)&bA[aOff[i][ks]];
#pragma unroll
      for (int j = 0; j < 4; ++j) bfr[j] = *(const bf16x8*)&bB[bOff[j][ks]];
      __builtin_amdgcn_s_setprio(1);
#pragma unroll
      for (int i = 0; i < 8; ++i)
#pragma unroll
        for (int j = 0; j < 4; ++j)
          acc[i][j] = __builtin_amdgcn_mfma_f32_16x16x32_bf16(
              af[i], bfr[j], acc[i][j], 0, 0, 0);
      __builtin_amdgcn_s_setprio(0);
    }
    __builtin_amdgcn_sched_barrier(0);     // no next-iter GLDS hoisted above
    __builtin_amdgcn_s_barrier();          // all waves done reading buf[cur]
  }

  float bj[4];
  if constexpr (MODE == 2) {
#pragma unroll
    for (int j = 0; j < 4; ++j) bj[j] = bias[n0 + wn * 64 + j * 16 + r16];
  }
#pragma unroll
  for (int i = 0; i < 8; ++i) {
    const int row0 = m0 + wm * 128 + i * 16 + g * 4;
#pragma unroll
    for (int j = 0; j < 4; ++j) {
      const int colb = n0 + wn * 64 + j * 16;
      const int col = colb + r16;
      if constexpr (MODE == 0) {
        if (colb < 2048) {
#pragma unroll
          for (int r = 0; r < 4; ++r)
            outb[(size_t)(row0 + r) * 2048 + col] = f2b(acc[i][j][r]);
        } else {
          const int b = row0 >> 11, s0 = row0 & 2047;
          us4 pk;
          pk.x = f2b(acc[i][j][0]); pk.y = f2b(acc[i][j][1]);
          pk.z = f2b(acc[i][j][2]); pk.w = f2b(acc[i][j][3]);
          *(us4*)&vt[((size_t)b * 1024 + (col - 2048)) * 2048 + s0] = pk;
        }
      } else {
#pragma unroll
        for (int r = 0; r < 4; ++r) {
          const float x = acc[i][j][r] + bj[j];
          const float u = x * (0.7978845608028654f + 0.03567740814f * x * x);
          const float e = __builtin_amdgcn_exp2f(u * 2.885390081777927f);
          const float th = 1.0f - 2.0f * __builtin_amdgcn_rcpf(e + 1.0f);
          outb[(size_t)(row0 + r) * N + col] = f2b(0.5f * x * (1.0f + th));
        }
      }
    }
  }
}

// ---------------------------------------------------------------------------
// GEMM: C[M,N] = A[M,K](bf16) * B^T, B stored [N,K]. BMx128 tile, 4 waves.
// NOW counted-vmcnt (same pipeline as gemm256): stage = ACH+4 = 6 GLDS, raw
// s_barrier + s_waitcnt vmcnt(6) so next-tile loads stay in flight across
// the barrier. Used for N=1024 GEMMs (Wo, FFN-down).
// MODE 1: out_f32 = acc + resid
// MODE 3: out_f32 = acc + bias + resid
// ---------------------------------------------------------------------------
template <int MODE, int BM>
__global__ void __launch_bounds__(256) gemm_bt(
    const unsigned short* __restrict__ A, const unsigned short* __restrict__ B,
    int K, int N,
    float* __restrict__ outf, const float* __restrict__ bias,
    const float* __restrict__ resid) {
  constexpr int WN = (BM == 128) ? 2 : 4;   // waves along N
  constexpr int NJ = 128 / (16 * WN);       // N-fragments per wave
  constexpr int ACH = BM / 32;              // A staging passes
  __shared__ unsigned short lA[2][BM * 64];
  __shared__ unsigned short lB[2][128 * 64];
  const int t = threadIdx.x, lane = t & 63;
  const int w = t >> 6, wm = w / WN, wn = w % WN;
  const int r16 = lane & 15, g = lane >> 4;
  const int m0 = blockIdx.x * BM, n0 = blockIdx.y * 128;

  const unsigned short* aSrc[ACH];
  const unsigned short* bSrc[4];
#pragma unroll
  for (int p = 0; p < ACH; ++p) {
    const int ci = t + p * 256, m = ci >> 3, cs = ci & 7;
    aSrc[p] = A + (size_t)(m0 + m) * K + (cs ^ (m & 7)) * 8;
  }
#pragma unroll
  for (int p = 0; p < 4; ++p) {
    const int ci = t + p * 256, m = ci >> 3, cs = ci & 7;
    bSrc[p] = B + (size_t)(n0 + m) * K + (cs ^ (m & 7)) * 8;
  }

  int aOff[4][2], bOff[NJ][2];
#pragma unroll
  for (int i = 0; i < 4; ++i)
#pragma unroll
    for (int ks = 0; ks < 2; ++ks) {
      const int m = wm * 64 + i * 16 + r16, kb = ks * 4 + g;
      aOff[i][ks] = ((m << 3) + (kb ^ (m & 7))) << 3;
    }
#pragma unroll
  for (int j = 0; j < NJ; ++j)
#pragma unroll
    for (int ks = 0; ks < 2; ++ks) {
      const int n = wn * (16 * NJ) + j * 16 + r16, kb = ks * 4 + g;
      bOff[j][ks] = ((n << 3) + (kb ^ (n & 7))) << 3;
    }

  auto stage = [&](int buf, int kt) {
    const int off = kt * 64;
#pragma unroll
    for (int p = 0; p < ACH; ++p)
      GLDS(aSrc[p] + off, &lA[buf][(t + p * 256) * 8]);
#pragma unroll
    for (int p = 0; p < 4; ++p)
      GLDS(bSrc[p] + off, &lB[buf][(t + p * 256) * 8]);
  };

  f32x4 acc[4][NJ] = {};
  const int nkt = K >> 6;
  stage(0, 0);
  for (int kt = 0; kt < nkt; ++kt) {
    const int cur = kt & 1;
    if (kt + 1 < nkt) {
      stage(cur ^ 1, kt + 1);  // 6 loads into buf[cur^1], left in flight
      if constexpr (ACH == 2)
        asm volatile("s_waitcnt vmcnt(6)" ::: "memory");  // buf[cur] landed
      else
        asm volatile("s_waitcnt vmcnt(8)" ::: "memory");
    } else {
      asm volatile("s_waitcnt vmcnt(0)" ::: "memory");
    }
    __builtin_amdgcn_s_barrier();          // all waves: buf[cur] staged
    __builtin_amdgcn_sched_barrier(0);     // no LDS reads hoisted above
    const unsigned short* bA = lA[cur];
    const unsigned short* bB = lB[cur];
#pragma unroll
    for (int ks = 0; ks < 2; ++ks) {
      bf16x8 af[4], bfr[NJ];
#pragma unroll
      for (int i = 0; i < 4; ++i) af[i] = *(const bf16x8*)&bA[aOff[i][ks]];
#pragma unroll
      for (int j = 0; j < NJ; ++j) bfr[j] = *(const bf16x8*)&bB[bOff[j][ks]];
      __builtin_amdgcn_s_setprio(1);
#pragma unroll
      for (int i = 0; i < 4; ++i)
#pragma unroll
        for (int j = 0; j < NJ; ++j)
          acc[i][j] = __builtin_amdgcn_mfma_f32_16x16x32_bf16(
              af[i], bfr[j], acc[i][j], 0, 0, 0);
      __builtin_amdgcn_s_setprio(0);
    }
    __builtin_amdgcn_sched_barrier(0);     // no next-iter GLDS hoisted above
    __builtin_amdgcn_s_barrier();          // all waves done reading buf[cur]
  }

  float bj[NJ];
  if constexpr (MODE == 3) {
#pragma unroll
    for (int j = 0; j < NJ; ++j)
      bj[j] = bias[n0 + wn * (16 * NJ) + j * 16 + r16];
  }
#pragma unroll
  for (int i = 0; i < 4; ++i) {
    const int row0 = m0 + wm * 64 + i * 16 + g * 4;
#pragma unroll
    for (int j = 0; j < NJ; ++j) {
      const int col = n0 + wn * (16 * NJ) + j * 16 + r16;
      if constexpr (MODE == 1) {
#pragma unroll
        for (int r = 0; r < 4; ++r) {
          const size_t idx = (size_t)(row0 + r) * N + col;
          outf[idx] = acc[i][j][r] + resid[idx];
        }
      } else {
#pragma unroll
        for (int r = 0; r < 4; ++r) {
          const size_t idx = (size_t)(row0 + r) * N + col;
          outf[idx] = acc[i][j][r] + bj[j] + resid[idx];
        }
      }
    }
  }
}

// ---------------------------------------------------------------------------
// Flash attention (causal), load-balanced: block j handles q-tiles j and 31-j
// (33 compute-steps/block, one shared K/V staging pass). Grid (16,16,2),
// 4 waves. Round-3 structure + micro-opts that passed in round 4:
// T5 setprio around MFMA, T13 defer-max (THR=44 raw-score units),
// cvt_pk_bf16 P-packing, XOR-swizzled per-wave lP.
// ---------------------------------------------------------------------------
__global__ void __launch_bounds__(256) attn_kernel(
    const unsigned short* __restrict__ qk, const unsigned short* __restrict__ vt,
    unsigned short* __restrict__ obuf) {
  const int j = blockIdx.x, h = blockIdx.y, bb = blockIdx.z;
  const int t = threadIdx.x, lane = t & 63, w = t >> 6;
  const int r16 = lane & 15, g = lane >> 4;
  __shared__ unsigned short lK[2][64 * 64];
  __shared__ unsigned short lV[2][64 * 64];
  __shared__ unsigned short lP[4][16 * 64];

  const int qtA = j, qtB = 31 - j;   // qtA <= qtB
  const int ktmax = qtB;
  const int qrowA = qtA * 64 + w * 16 + r16;
  const int qrowB = qtB * 64 + w * 16 + r16;
  const float CE = 0.18033688011112042f;  // (1/8) * log2(e)

  bf16x8 qfA[2], qfB[2];
  {
    const unsigned short* qa = qk + (size_t)(bb * 2048 + qrowA) * 2048 + h * 64;
    qfA[0] = *(const bf16x8*)(qa + g * 8);
    qfA[1] = *(const bf16x8*)(qa + 32 + g * 8);
    const unsigned short* qb = qk + (size_t)(bb * 2048 + qrowB) * 2048 + h * 64;
    qfB[0] = *(const bf16x8*)(qb + g * 8);
    qfB[1] = *(const bf16x8*)(qb + 32 + g * 8);
  }

  f32x4 accA[4] = {}, accB[4] = {};
  float mA = -3.0e38f, lA_ = 0.0f, mB = -3.0e38f, lB_ = 0.0f;

  auto stage = [&](int buf, int kt) {
    const int k0 = kt * 64;
#pragma unroll
    for (int p = 0; p < 2; ++p) {
      const int ci = t + p * 256;
      const int r = ci >> 3, cs = ci & 7;
      const int cb = cs ^ (r & 7);
      GLDS(qk + (size_t)(bb * 2048 + k0 + r) * 2048 + 1024 + h * 64 + cb * 8,
           &lK[buf][ci * 8]);
      GLDS(vt + ((size_t)bb * 1024 + h * 64 + r) * 2048 + k0 + cb * 8,
           &lV[buf][ci * 8]);
    }
  };

  const int pswz = (r16 & 7) << 3;  // lP XOR swizzle (8-elem granules)

  auto flash_step = [&](const bf16x8* qf, f32x4* accO, float& mrun,
                        float& lrun, int qrow, bool diag, int k0, int cur) {
    f32x4 s[4] = {};
    __builtin_amdgcn_s_setprio(1);
#pragma unroll
    for (int ks = 0; ks < 2; ++ks)
#pragma unroll
      for (int mt = 0; mt < 4; ++mt) {
        const int r = mt * 16 + r16, db = ks * 4 + g;
        const bf16x8 kf =
            *(const bf16x8*)&lK[cur][((r << 3) + (db ^ (r & 7))) << 3];
        s[mt] = __builtin_amdgcn_mfma_f32_16x16x32_bf16(kf, qf[ks], s[mt],
                                                        0, 0, 0);
      }
    __builtin_amdgcn_s_setprio(0);
    if (diag) {
#pragma unroll
      for (int mt = 0; mt < 4; ++mt)
#pragma unroll
        for (int r = 0; r < 4; ++r)
          if (k0 + mt * 16 + g * 4 + r > qrow) s[mt][r] = -3.0e38f;
    }
    float tmax = -3.0e38f;
#pragma unroll
    for (int mt = 0; mt < 4; ++mt)
#pragma unroll
      for (int r = 0; r < 4; ++r) tmax = fmaxf(tmax, s[mt][r]);
    tmax = fmaxf(tmax, __shfl_xor(tmax, 16));
    tmax = fmaxf(tmax, __shfl_xor(tmax, 32));
    // T13 defer-max: only rescale when the running max grew materially
    if (!__all(tmax <= mrun + 44.0f)) {
      const float mnew = fmaxf(mrun, tmax);
      const float fac = __builtin_amdgcn_exp2f((mrun - mnew) * CE);
      lrun *= fac;
      float fr[4];
#pragma unroll
      for (int r = 0; r < 4; ++r) fr[r] = __shfl(fac, g * 4 + r);
#pragma unroll
      for (int nb = 0; nb < 4; ++nb)
#pragma unroll
        for (int r = 0; r < 4; ++r) accO[nb][r] *= fr[r];
      mrun = mnew;
    }
    float pv[4][4];
    float tsum = 0.0f;
#pragma unroll
    for (int mt = 0; mt < 4; ++mt)
#pragma unroll
      for (int r = 0; r < 4; ++r) {
        pv[mt][r] = __builtin_amdgcn_exp2f((s[mt][r] - mrun) * CE);
        tsum += pv[mt][r];
      }
    tsum += __shfl_xor(tsum, 16);
    tsum += __shfl_xor(tsum, 32);
    lrun += tsum;
    // write P^T (per-wave region, XOR-swizzled, cvt_pk packed)
#pragma unroll
    for (int mt = 0; mt < 4; ++mt) {
      u32x2 pk;
      pk.x = cvt_pk_bf16(pv[mt][0], pv[mt][1]);
      pk.y = cvt_pk_bf16(pv[mt][2], pv[mt][3]);
      *(u32x2*)&lP[w][r16 * 64 + ((mt * 16 + g * 4) ^ pswz)] = pk;
    }
    __builtin_amdgcn_s_setprio(1);
#pragma unroll
    for (int ks = 0; ks < 2; ++ks) {
      const bf16x8 pa =
          *(const bf16x8*)&lP[w][r16 * 64 + ((ks * 32 + g * 8) ^ pswz)];
#pragma unroll
      for (int nb = 0; nb < 4; ++nb) {
        const int d = nb * 16 + r16, kb = ks * 4 + g;
        const bf16x8 vf =
            *(const bf16x8*)&lV[cur][((d << 3) + (kb ^ (d & 7))) << 3];
        accO[nb] = __builtin_amdgcn_mfma_f32_16x16x32_bf16(pa, vf, accO[nb],
                                                           0, 0, 0);
      }
    }
    __builtin_amdgcn_s_setprio(0);
  };

  stage(0, 0);
  __syncthreads();
  int cur = 0;
  for (int kt = 0; kt <= ktmax; ++kt) {
    if (kt < ktmax) stage(cur ^ 1, kt + 1);
    flash_step(qfB, accB, mB, lB_, qrowB, kt == qtB, kt * 64, cur);
    if (kt <= qtA)
      flash_step(qfA, accA, mA, lA_, qrowA, kt == qtA, kt * 64, cur);
    __syncthreads();  // drains vmcnt: staged kt+1 complete + lK/lV[cur] free
    cur ^= 1;
  }

  auto epilogue = [&](const f32x4* accO, float lrun, int q0) {
    const float li = 1.0f / lrun;
    float lr_[4];
#pragma unroll
    for (int r = 0; r < 4; ++r) lr_[r] = __shfl(li, g * 4 + r);
#pragma unroll
    for (int nb = 0; nb < 4; ++nb)
#pragma unroll
      for (int r = 0; r < 4; ++r) {
        const int row = bb * 2048 + q0 + w * 16 + g * 4 + r;
        const int col = h * 64 + nb * 16 + r16;
        obuf[(size_t)row * 1024 + col] = f2b(accO[nb][r] * lr_[r]);
      }
  };
  epilogue(accA, lA_, qtA * 64);
  epilogue(accB, lB_, qtB * 64);
}

// ---------------------------------------------------------------------------
extern "C" void kernel_launch(void* const* d_in, const int* in_sizes, int n_in,
                              void* d_out, int out_size, void* d_ws,
                              size_t ws_size, hipStream_t stream) {
  const float* hs   = (const float*)d_in[0];
  const float* Wq   = (const float*)d_in[1];
  const float* Wk   = (const float*)d_in[2];
  const float* Wv   = (const float*)d_in[3];
  const float* Wo   = (const float*)d_in[4];
  const float* W1   = (const float*)d_in[5];
  const float* b1   = (const float*)d_in[6];
  const float* W2   = (const float*)d_in[7];
  const float* b2   = (const float*)d_in[8];
  const float* ln1s = (const float*)d_in[9];
  const float* ln1b = (const float*)d_in[10];
  const float* ln2s = (const float*)d_in[11];
  const float* ln2b = (const float*)d_in[12];
  float* out = (float*)d_out;

  char* ws = (char*)d_ws;
  unsigned short* wqkvT = (unsigned short*)(ws + 0);          //  6 MB [3072][1024]
  unsigned short* woT   = (unsigned short*)(ws + 6291456);    //  2 MB [1024][1024]
  unsigned short* w1T   = (unsigned short*)(ws + 8388608);    //  8 MB [4096][1024]
  unsigned short* w2T   = (unsigned short*)(ws + 16777216);   //  8 MB [1024][4096]
  float*          hid   = (float*)(ws + 25165824);            // 16 MB [4096][1024]
  unsigned short* xb    = (unsigned short*)(ws + 41943040);   //  8 MB [4096][1024]
  char*           big   = ws + 50331648;                      // 32 MB region
  unsigned short* qkb   = (unsigned short*)(big);             // 16 MB [4096][2048]
  unsigned short* vtb   = (unsigned short*)(big + 16777216);  //  8 MB [2][1024][2048]
  unsigned short* ob    = (unsigned short*)(big + 25165824);  //  8 MB [4096][1024]
  unsigned short* h1    = (unsigned short*)(big);             // 32 MB (reuse) [4096][4096]

  // weights -> bf16, transposed
  transpose_w<<<dim3(32, 32), 256, 0, stream>>>(Wq, wqkvT, 1024, 1024);
  transpose_w<<<dim3(32, 32), 256, 0, stream>>>(Wk, wqkvT + 1024 * 1024, 1024, 1024);
  transpose_w<<<dim3(32, 32), 256, 0, stream>>>(Wv, wqkvT + 2 * 1024 * 1024, 1024, 1024);
  transpose_w<<<dim3(32, 32), 256, 0, stream>>>(Wo, woT, 1024, 1024);
  transpose_w<<<dim3(128, 32), 256, 0, stream>>>(W1, w1T, 1024, 4096);
  transpose_w<<<dim3(32, 128), 256, 0, stream>>>(W2, w2T, 4096, 1024);

  // LN1
  ln_kernel<<<4096, 256, 0, stream>>>(hs, ln1s, ln1b, xb);
  // QKV projection (256^2 counted-vmcnt pipeline; V written transposed)
  gemm256<0><<<dim3(16, 12), 512, 0, stream>>>(xb, wqkvT, 1024, 3072,
                                               qkb, nullptr, vtb);
  // attention (load-balanced paired q-tiles + VALU micro-opts)
  attn_kernel<<<dim3(16, 16, 2), 256, 0, stream>>>(qkb, vtb, ob);
  // output projection + residual (BM=64, counted-vmcnt)
  gemm_bt<1, 64><<<dim3(64, 8), 256, 0, stream>>>(ob, woT, 1024, 1024,
                                                  hid, nullptr, hs);
  // LN2
  ln_kernel<<<4096, 256, 0, stream>>>(hid, ln2s, ln2b, xb);
  // FFN up + GELU (tanh approx), 256^2 counted-vmcnt pipeline
  gemm256<2><<<dim3(16, 16), 512, 0, stream>>>(xb, w1T, 1024, 4096,
                                               h1, b1, nullptr);
  // FFN down + bias + residual -> out (BM=64, counted-vmcnt)
  gemm_bt<3, 64><<<dim3(64, 8), 256, 0, stream>>>(h1, w2T, 4096, 1024,
                                                  out, b2, hid);
}